// Round 8
// baseline (579.684 us; speedup 1.0000x reference)
//
#include <hip/hip_runtime.h>

typedef __bf16 bf16_t;
typedef __bf16 bf16x8 __attribute__((ext_vector_type(8)));
typedef float f32x4 __attribute__((ext_vector_type(4)));
typedef int   int4v __attribute__((ext_vector_type(4)));

#define LOG2E 1.4426950408889634f

template<int CTRL>
__device__ __forceinline__ float qperm(float x) {
  return __builtin_bit_cast(float,
      __builtin_amdgcn_update_dpp(0, __builtin_bit_cast(int, x), CTRL, 0xF, 0xF, true));
}

// LDS-only barrier: does NOT drain vmcnt, so global loads/stores stay in
// flight across steps (compiler's __syncthreads drains vmcnt(0) every step).
__device__ __forceinline__ void lds_barrier() {
  asm volatile("s_waitcnt lgkmcnt(0)\n\ts_barrier" ::: "memory");
}

// ---------------------------------------------------------------------------
// K1: preT[dir][r][t] = (Wih_dir @ x[t_x]) + bih + bhh, gate-interleaved rows:
//     r = 4n + p  <->  original row j = 125*p + n   (n<125 valid, else 0)
//     t_x = t (fwd) or 511-t (bwd).
// MFMA GEMM with bf16 hi/lo split: fp32-exact to ~2^-18.
// Also resets the lstm heater done-flag (stream order: pre completes before
// lstm launches, so the reset is always visible).
// ---------------------------------------------------------------------------
__global__ __launch_bounds__(256) void pre_kernel(
    const float* __restrict__ x,     // [512][125]
    const float* __restrict__ Wih_f, const float* __restrict__ bih_f,
    const float* __restrict__ bhh_f,
    const float* __restrict__ Wih_b, const float* __restrict__ bih_b,
    const float* __restrict__ bhh_b,
    float* __restrict__ preT,        // [2][512 r][512 t]
    unsigned* __restrict__ done)
{
  if (blockIdx.x == 0 && threadIdx.x == 0)
    __hip_atomic_store(done, 0u, __ATOMIC_RELAXED, __HIP_MEMORY_SCOPE_AGENT);

  const int dir = blockIdx.x >> 5;
  const int T   = blockIdx.x & 31;
  const float* __restrict__ Wih = dir ? Wih_b : Wih_f;
  const float* __restrict__ bih = dir ? bih_b : bih_f;
  const float* __restrict__ bhh = dir ? bhh_b : bhh_f;

  const int tid = threadIdx.x;
  const int wv  = tid >> 6;
  const int lane = tid & 63;
  const int q = lane >> 4, cc = lane & 15;

  // A fragments for row-tile T: row r = 16T + cc, k = 32ks + 8q + j
  const int r  = 16 * T + cc;
  const int na = r >> 2, pa = r & 3;
  const bool vld = (na < 125);
  const float* __restrict__ Wr = Wih + (vld ? (125 * pa + na) * 125 : 0);

  bf16x8 whi[4], wlo[4];
  #pragma unroll
  for (int ks = 0; ks < 4; ++ks) {
    #pragma unroll
    for (int j = 0; j < 8; ++j) {
      int k = 32 * ks + 8 * q + j;
      float wvv = (vld && k < 125) ? Wr[k] : 0.0f;
      bf16_t hi = (bf16_t)wvv;
      whi[ks][j] = hi;
      wlo[ks][j] = (bf16_t)(wvv - (float)hi);
    }
  }

  // bias for the 4 output rows this lane stores
  float bias[4];
  #pragma unroll
  for (int reg = 0; reg < 4; ++reg) {
    int ro = 16 * T + 4 * q + reg;
    int no = ro >> 2, po = ro & 3;
    bias[reg] = (no < 125) ? (bih[125 * po + no] + bhh[125 * po + no]) : 0.0f;
  }

  for (int i = 0; i < 8; ++i) {
    const int tt = 8 * wv + i;
    const int t  = 16 * tt + cc;
    const int trow = dir ? (511 - t) : t;
    const float* __restrict__ xr = x + trow * 125;

    f32x4 acc = (f32x4)0.0f;
    #pragma unroll
    for (int ks = 0; ks < 4; ++ks) {
      bf16x8 xhi, xlo;
      #pragma unroll
      for (int j = 0; j < 8; ++j) {
        int k = 32 * ks + 8 * q + j;
        float xv = (k < 125) ? xr[k] : 0.0f;
        bf16_t hi = (bf16_t)xv;
        xhi[j] = hi;
        xlo[j] = (bf16_t)(xv - (float)hi);
      }
      acc = __builtin_amdgcn_mfma_f32_16x16x32_bf16(whi[ks], xhi, acc, 0, 0, 0);
      acc = __builtin_amdgcn_mfma_f32_16x16x32_bf16(whi[ks], xlo, acc, 0, 0, 0);
      acc = __builtin_amdgcn_mfma_f32_16x16x32_bf16(wlo[ks], xhi, acc, 0, 0, 0);
    }
    #pragma unroll
    for (int reg = 0; reg < 4; ++reg) {
      int ro = 16 * T + 4 * q + reg;
      preT[dir * 262144 + ro * 512 + 16 * tt + cc] = acc[reg] + bias[reg];
    }
  }
}

// ---------------------------------------------------------------------------
// K2: sequential LSTM.  grid = 256 blocks: blocks 0,1 do the recurrence
// (proven round-0 MFMA structure); blocks 2..255 are BOUNDED heaters —
// dependent-FMA busy loops that keep every CU non-idle so SCLK does not
// fall to the DVFS floor during this 2-CU serial phase (round-5 evidence:
// idle-spin dropped the chip to ~1/4 clock).  Heater termination does NOT
// depend on cross-block communication: a hard s_memrealtime cap (~250us at
// the 100MHz RTC; bounded 65us..1ms for any plausible RTC rate) guarantees
// exit even if the done-flag is never observed.  Flag gives early exit.
// ---------------------------------------------------------------------------
__global__ __launch_bounds__(512) void lstm_kernel(
    const float* __restrict__ Whh_f, const float* __restrict__ Whh_b,
    const float* __restrict__ pre,   // [2][512 r][512 t]
    bf16_t* __restrict__ h_all,      // [512][256]
    unsigned* __restrict__ done)
{
  const int tid  = threadIdx.x;

  if (blockIdx.x >= 2) {
    // heater: busy-residency, low power (dependent fma chain), hard-bounded
    const unsigned long long t0 = __builtin_amdgcn_s_memrealtime();
    float a = 1.0f + (float)tid;
    const float b = 1.0000001f;
    for (;;) {
      unsigned d = __hip_atomic_load(done, __ATOMIC_ACQUIRE,
                                     __HIP_MEMORY_SCOPE_AGENT);
      if (d >= 2u) break;
      if (__builtin_amdgcn_s_memrealtime() - t0 > 25000ull) break;
      #pragma unroll
      for (int it = 0; it < 256; ++it) a = fmaf(a, b, 1e-7f);
    }
    asm volatile("" :: "v"(a));   // keep the chain alive (no DCE)
    return;
  }

  const int dir = blockIdx.x;
  const float* __restrict__ Whh = dir ? Whh_b : Whh_f;

  const int lane = tid & 63;
  const int w    = tid >> 6;      // wave 0..7
  const int q    = lane >> 4;     // 0..3
  const int cc   = lane & 15;
  const int lt   = cc >> 2;       // local tile 0..3
  const int p    = cc & 3;        // gate index

  // ---- pass 1: global max |Whh| over used elements ----
  float wm = 0.0f;
  #pragma unroll
  for (int LT = 0; LT < 4; ++LT) {
    int rr = 16 * (4 * w + LT) + cc;
    int nn = rr >> 2, pp = rr & 3;
    if (nn < 125) {
      const float* __restrict__ Wrow = Whh + (125 * pp + nn) * 125;
      #pragma unroll
      for (int ks = 0; ks < 2; ++ks)
        #pragma unroll
        for (int jj = 0; jj < 16; ++jj) {
          int k = 64 * ks + 16 * q + jj;
          if (k < 125) wm = fmaxf(wm, fabsf(Wrow[k]));
        }
    }
  }
  #pragma unroll
  for (int off = 1; off < 64; off <<= 1)
    wm = fmaxf(wm, __shfl_xor(wm, off));
  __shared__ float wmx[8];
  if (lane == 0) wmx[w] = wm;
  __syncthreads();
  float wmax = wmx[0];
  #pragma unroll
  for (int u = 1; u < 8; ++u) wmax = fmaxf(wmax, wmx[u]);
  const float s_w  = 127.0f / wmax;
  const float invq = wmax / (127.0f * 127.0f);   // D -> W@h

  // ---- pass 2: quantize A fragments (i8, k = 64ks + 16q + jj) ----
  int4v afrag[4][2];
  #pragma unroll
  for (int LT = 0; LT < 4; ++LT) {
    int rr = 16 * (4 * w + LT) + cc;
    int nn = rr >> 2, pp = rr & 3;
    bool avld = (nn < 125);
    const float* __restrict__ Wrow = Whh + (avld ? (125 * pp + nn) * 125 : 0);
    #pragma unroll
    for (int ks = 0; ks < 2; ++ks) {
      int4v v;
      #pragma unroll
      for (int word = 0; word < 4; ++word) {
        int b = 0;
        #pragma unroll
        for (int byte = 0; byte < 4; ++byte) {
          int jj = 4 * word + byte;
          int k  = 64 * ks + 16 * q + jj;
          int qv = 0;
          if (avld && k < 125)
            qv = (int)__builtin_rintf(Wrow[k] * s_w);
          b |= (qv & 0xFF) << (8 * byte);
        }
        v[word] = b;
      }
      afrag[LT][ks] = v;
    }
  }

  __shared__ __align__(16) char hbuf[2][128];    // int8 h, double buffered
  if (tid < 256) hbuf[tid >> 7][tid & 127] = 0;
  // zero h_all pad columns once (dir 0 only)
  if (dir == 0) {
    #pragma unroll
    for (int u = 0; u < 6; ++u) h_all[tid * 256 + 250 + u] = (bf16_t)0.0f;
  }
  __syncthreads();

  const int   r_lane = 64 * w + 16 * lt + 4 * q + p;
  const int   nset   = 16 * w + 4 * lt + q;
  const float mult   = (p == 2) ? (-2.0f * LOG2E) : (-LOG2E);
  const float sA     = (p == 2) ? 2.0f : 1.0f;
  const float sB     = (p == 2) ? -1.0f : 0.0f;
  const float dscale = mult * invq;              // int D -> exp2 argument
  const float* __restrict__ preR = pre + dir * 262144 + r_lane * 512;
  float c = 0.0f;

  float4 pv_cur = *(const float4*)preR;

  for (int g = 0; g < 128; ++g) {
    float4 pv_nxt = make_float4(0.f, 0.f, 0.f, 0.f);
    if (g < 127) pv_nxt = *(const float4*)(preR + 4 * (g + 1));

    #pragma unroll
    for (int s4 = 0; s4 < 4; ++s4) {
      const int step = 4 * g + s4;
      const int cur  = s4 & 1, nxt = cur ^ 1;
      const float pv = (s4 == 0) ? pv_cur.x : (s4 == 1) ? pv_cur.y
                     : (s4 == 2) ? pv_cur.z : pv_cur.w;
      const float pvm = mult * pv;               // off critical path

      int4v b0 = *(const int4v*)&hbuf[cur][16 * q];
      int4v b1 = *(const int4v*)&hbuf[cur][64 + 16 * q];

      int4v acc[4];
      #pragma unroll
      for (int LT = 0; LT < 4; ++LT) {
        int4v a = (int4v)0;
        a = __builtin_amdgcn_mfma_i32_16x16x64_i8(afrag[LT][0], b0, a, 0, 0, 0);
        a = __builtin_amdgcn_mfma_i32_16x16x64_i8(afrag[LT][1], b1, a, 0, 0, 0);
        acc[LT] = a;
      }

      // select D for (lt, p) from own registers
      int gl[4];
      #pragma unroll
      for (int LT = 0; LT < 4; ++LT) {
        int a01 = (p & 1) ? acc[LT][1] : acc[LT][0];
        int a23 = (p & 1) ? acc[LT][3] : acc[LT][2];
        gl[LT] = (p & 2) ? a23 : a01;
      }
      int b01 = (lt & 1) ? gl[1] : gl[0];
      int b23 = (lt & 1) ? gl[3] : gl[2];
      int gsel = (lt & 2) ? b23 : b01;

      // uniform activation: y = sigmoid(scale*(W@h + pv)); act = sA*y + sB
      float gf  = (float)gsel;
      float xg  = fmaf(gf, dscale, pvm);
      float e   = __builtin_amdgcn_exp2f(xg);
      float y   = __builtin_amdgcn_rcpf(1.0f + e);
      float act = fmaf(y, sA, sB);

      // quad: p0=i, p1=f, p2=g~, p3=o  (flat broadcast tree)
      float b_i = qperm<0x00>(act);
      float b_f = qperm<0x55>(act);
      float b_g = qperm<0xAA>(act);
      float b_o = qperm<0xFF>(act);
      c = fmaf(b_f, c, b_i * b_g);               // c = f*c + i*g~
      float e2 = __builtin_amdgcn_exp2f(-2.0f * LOG2E * c);
      float tc = fmaf(__builtin_amdgcn_rcpf(1.0f + e2), 2.0f, -1.0f);
      float h  = b_o * tc;

      if (p == 0) {
        int qh = (int)__builtin_rintf(h * 127.0f);
        hbuf[nxt][nset] = (char)qh;              // pad units stay exactly 0
        if (nset < 125) {
          int t_orig = dir ? (511 - step) : step;
          h_all[t_orig * 256 + dir * 125 + nset] = (bf16_t)h;
        }
      }
      lds_barrier();
    }
    pv_cur = pv_nxt;
  }

  // signal heaters: this direction is done
  __syncthreads();
  if (tid == 0) {
    __threadfence();
    __hip_atomic_fetch_add(done, 1u, __ATOMIC_RELEASE,
                           __HIP_MEMORY_SCOPE_AGENT);
  }
}

// ---------------------------------------------------------------------------
// K3: Ea[j][m] = exp2(C2 * (h @ W1[:, :250].T)[j][m])
//     Eb[j][m] = exp2(C2 * ((h @ W1[:, 250:].T)[j][m] + b1[m]))
// C2 = 2*log2(e).  Storing the EXPONENTIALS halves K4's transcendental count.
// bf16 MFMA, one 16x16 tile/wave.
// ---------------------------------------------------------------------------
__global__ __launch_bounds__(256) void qgemm_kernel(
    const bf16_t* __restrict__ h_all, // [512][256]
    const float* __restrict__ W1,     // [512][500]
    const float* __restrict__ b1,     // [512]
    float* __restrict__ Ea,           // [512][512]
    float* __restrict__ Eb)           // [512][512]
{
  const int tid  = threadIdx.x;
  const int wv   = tid >> 6;
  const int lane = tid & 63;
  const int q    = lane >> 4, cc = lane & 15;
  const int bj   = blockIdx.x & 31;    // j tile
  const int bm   = blockIdx.x >> 5;    // m group
  const int m    = bm * 64 + wv * 16 + cc;   // [0,1024)
  const int j0   = bj * 16;
  const int jA   = j0 + cc;

  const bool isB = (m >= 512);
  const int  row = isB ? (m - 512) : m;
  const int  cof = isB ? 250 : 0;

  f32x4 acc = (f32x4)0.0f;
  #pragma unroll
  for (int ks = 0; ks < 8; ++ks) {
    int kb = 32 * ks + 8 * q;
    bf16x8 a = *(const bf16x8*)&h_all[jA * 256 + kb];
    bf16x8 b;
    #pragma unroll
    for (int jj = 0; jj < 8; ++jj) {
      int k = kb + jj;
      float v = (k < 250) ? W1[row * 500 + cof + k] : 0.0f;
      b[jj] = (bf16_t)v;
    }
    acc = __builtin_amdgcn_mfma_f32_16x16x32_bf16(a, b, acc, 0, 0, 0);
  }

  const float C2 = 2.0f * LOG2E;
  #pragma unroll
  for (int reg = 0; reg < 4; ++reg) {
    int j = j0 + 4 * q + reg;
    float v = acc[reg];
    if (!isB) Ea[j * 512 + m] = __builtin_amdgcn_exp2f(C2 * v);
    else      Eb[j * 512 + (m - 512)] =
                  __builtin_amdgcn_exp2f(C2 * (v + b1[m - 512]));
  }
}

// ---------------------------------------------------------------------------
// K4: out[i][j] = b2 + sum_k W2[k] * tanh(Pa[j,k]+Pb[i,k]+b1[k])
//     tanh = 1 - 2*rcp(1 + Ea[j,k]*Eb[i,k])   (exp2's precomputed in K3)
// k-PAIRED: one rcp per 2 k (exact algebra, overflow-safe).  512 blocks
// (2/CU -> 2 waves/SIMD hides rcp->fma latency), 16i x 32j tile.
// ---------------------------------------------------------------------------
__global__ __launch_bounds__(256) void outer_kernel(
    const float* __restrict__ Ea, const float* __restrict__ Eb,
    const float* __restrict__ W2, const float* __restrict__ b2,
    float* __restrict__ out)
{
  __shared__ float sa2[2][32][36];   // [buf][j][k]
  __shared__ float sb2[2][16][36];   // [buf][i][k]
  __shared__ float sw[2][32];

  const int tid = threadIdx.x;
  const int bi  = blockIdx.x >> 4;       // 0..31 -> i tile of 16
  const int bjx = blockIdx.x & 15;       // 0..15 -> j tile of 32
  const int i0  = bi * 16, j0 = bjx * 32;
  const int ii  = tid & 15;              // output i
  const int jj2 = tid >> 4;              // output j pair: j0 + 2*jj2 + {0,1}

  const int lj  = tid & 31, lk4 = (tid >> 5) * 4;   // sa2 loader coords
  const int li  = tid & 15, lk4b = ((tid >> 4) & 7) * 4; // sb2 loader coords

  float accR0 = 0.0f, accR1 = 0.0f;
  float wsum = 0.0f;

  for (int kc = 0; kc < 16; ++kc) {
    const int buf = kc & 1;
    const int k0  = kc * 32;
    float4 va = *(const float4*)&Ea[(j0 + lj) * 512 + k0 + lk4];
    *(float4*)&sa2[buf][lj][lk4] = va;
    if (tid < 128) {
      float4 vb = *(const float4*)&Eb[(i0 + li) * 512 + k0 + lk4b];
      *(float4*)&sb2[buf][li][lk4b] = vb;
    }
    if (tid < 32) sw[buf][tid] = W2[k0 + tid];
    __syncthreads();

    #pragma unroll 4
    for (int kk = 0; kk < 32; kk += 2) {
      float2 wv = *(const float2*)&sw[buf][kk];
      float2 bv = *(const float2*)&sb2[buf][ii][kk];
      float2 a0 = *(const float2*)&sa2[buf][2 * jj2 + 0][kk];
      float2 a1 = *(const float2*)&sa2[buf][2 * jj2 + 1][kk];
      wsum += wv.x + wv.y;
      {
        float t1  = fmaf(a0.x, bv.x, 1.0f);
        float t2  = fmaf(a0.y, bv.y, 1.0f);
        float den = t1 * t2;
        float num = fmaf(wv.x, t2, wv.y * t1);
        accR0 = fmaf(num, __builtin_amdgcn_rcpf(den), accR0);
      }
      {
        float t1  = fmaf(a1.x, bv.x, 1.0f);
        float t2  = fmaf(a1.y, bv.y, 1.0f);
        float den = t1 * t2;
        float num = fmaf(wv.x, t2, wv.y * t1);
        accR1 = fmaf(num, __builtin_amdgcn_rcpf(den), accR1);
      }
    }
  }

  const float bb = b2[0];
  float2 o;
  o.x = wsum - 2.0f * accR0 + bb;
  o.y = wsum - 2.0f * accR1 + bb;
  *(float2*)&out[(i0 + ii) * 512 + j0 + 2 * jj2] = o;
}

// ---------------------------------------------------------------------------
extern "C" void kernel_launch(void* const* d_in, const int* in_sizes, int n_in,
                              void* d_out, int out_size, void* d_ws, size_t ws_size,
                              hipStream_t stream) {
  const float* emb   = (const float*)d_in[0];
  const float* Wih_f = (const float*)d_in[1];
  const float* Whh_f = (const float*)d_in[2];
  const float* bih_f = (const float*)d_in[3];
  const float* bhh_f = (const float*)d_in[4];
  const float* Wih_b = (const float*)d_in[5];
  const float* Whh_b = (const float*)d_in[6];
  const float* bih_b = (const float*)d_in[7];
  const float* bhh_b = (const float*)d_in[8];
  const float* W1    = (const float*)d_in[9];
  const float* b1    = (const float*)d_in[10];
  const float* W2    = (const float*)d_in[11];
  const float* b2    = (const float*)d_in[12];
  float* out = (float*)d_out;

  char* ws = (char*)d_ws;
  float*    pre   = (float*)ws;                                  // 2 MB
  bf16_t*   h_all = (bf16_t*)(ws + 2 * 1024 * 1024);             // 256 KB
  float*    Ea    = (float*)(ws + 2 * 1024 * 1024 + 256 * 1024); // 1 MB
  float*    Eb    = Ea + 512 * 512;                              // 1 MB
  unsigned* done  = (unsigned*)(ws + 4 * 1024 * 1024 + 256 * 1024 + 160 * 1024);

  pre_kernel<<<64, 256, 0, stream>>>(emb, Wih_f, bih_f, bhh_f,
                                     Wih_b, bih_b, bhh_b, pre, done);
  lstm_kernel<<<256, 512, 0, stream>>>(Whh_f, Whh_b, pre, h_all, done);
  qgemm_kernel<<<512, 256, 0, stream>>>(h_all, W1, b1, Ea, Eb);
  outer_kernel<<<512, 256, 0, stream>>>(Ea, Eb, W2, b2, out);
}

// Round 9
// 319.858 us; speedup vs baseline: 1.8123x; 1.8123x over previous
//
#include <hip/hip_runtime.h>

typedef __bf16 bf16_t;
typedef __bf16 bf16x8 __attribute__((ext_vector_type(8)));
typedef float f32x4 __attribute__((ext_vector_type(4)));
typedef int   int4v __attribute__((ext_vector_type(4)));

#define LOG2E 1.4426950408889634f

template<int CTRL>
__device__ __forceinline__ float qperm(float x) {
  return __builtin_bit_cast(float,
      __builtin_amdgcn_update_dpp(0, __builtin_bit_cast(int, x), CTRL, 0xF, 0xF, true));
}

// LDS-only barrier: does NOT drain vmcnt, so global loads/stores stay in
// flight across steps (compiler's __syncthreads drains vmcnt(0) every step).
__device__ __forceinline__ void lds_barrier() {
  asm volatile("s_waitcnt lgkmcnt(0)\n\ts_barrier" ::: "memory");
}

// ---------------------------------------------------------------------------
// K1: preT[dir][r][t] = (Wih_dir @ x[t_x]) + bih + bhh, gate-interleaved rows:
//     r = 4n + p  <->  original row j = 125*p + n   (n<125 valid, else 0)
//     t_x = t (fwd) or 511-t (bwd).
// MFMA GEMM with bf16 hi/lo split: fp32-exact to ~2^-18.  64 blocks.
// ---------------------------------------------------------------------------
__global__ __launch_bounds__(256) void pre_kernel(
    const float* __restrict__ x,     // [512][125]
    const float* __restrict__ Wih_f, const float* __restrict__ bih_f,
    const float* __restrict__ bhh_f,
    const float* __restrict__ Wih_b, const float* __restrict__ bih_b,
    const float* __restrict__ bhh_b,
    float* __restrict__ preT)        // [2][512 r][512 t]
{
  const int dir = blockIdx.x >> 5;
  const int T   = blockIdx.x & 31;
  const float* __restrict__ Wih = dir ? Wih_b : Wih_f;
  const float* __restrict__ bih = dir ? bih_b : bih_f;
  const float* __restrict__ bhh = dir ? bhh_b : bhh_f;

  const int tid = threadIdx.x;
  const int wv  = tid >> 6;
  const int lane = tid & 63;
  const int q = lane >> 4, cc = lane & 15;

  // A fragments for row-tile T: row r = 16T + cc, k = 32ks + 8q + j
  const int r  = 16 * T + cc;
  const int na = r >> 2, pa = r & 3;
  const bool vld = (na < 125);
  const float* __restrict__ Wr = Wih + (vld ? (125 * pa + na) * 125 : 0);

  bf16x8 whi[4], wlo[4];
  #pragma unroll
  for (int ks = 0; ks < 4; ++ks) {
    #pragma unroll
    for (int j = 0; j < 8; ++j) {
      int k = 32 * ks + 8 * q + j;
      float wvv = (vld && k < 125) ? Wr[k] : 0.0f;
      bf16_t hi = (bf16_t)wvv;
      whi[ks][j] = hi;
      wlo[ks][j] = (bf16_t)(wvv - (float)hi);
    }
  }

  // bias for the 4 output rows this lane stores
  float bias[4];
  #pragma unroll
  for (int reg = 0; reg < 4; ++reg) {
    int ro = 16 * T + 4 * q + reg;
    int no = ro >> 2, po = ro & 3;
    bias[reg] = (no < 125) ? (bih[125 * po + no] + bhh[125 * po + no]) : 0.0f;
  }

  for (int i = 0; i < 8; ++i) {
    const int tt = 8 * wv + i;
    const int t  = 16 * tt + cc;
    const int trow = dir ? (511 - t) : t;
    const float* __restrict__ xr = x + trow * 125;

    f32x4 acc = (f32x4)0.0f;
    #pragma unroll
    for (int ks = 0; ks < 4; ++ks) {
      bf16x8 xhi, xlo;
      #pragma unroll
      for (int j = 0; j < 8; ++j) {
        int k = 32 * ks + 8 * q + j;
        float xv = (k < 125) ? xr[k] : 0.0f;
        bf16_t hi = (bf16_t)xv;
        xhi[j] = hi;
        xlo[j] = (bf16_t)(xv - (float)hi);
      }
      acc = __builtin_amdgcn_mfma_f32_16x16x32_bf16(whi[ks], xhi, acc, 0, 0, 0);
      acc = __builtin_amdgcn_mfma_f32_16x16x32_bf16(whi[ks], xlo, acc, 0, 0, 0);
      acc = __builtin_amdgcn_mfma_f32_16x16x32_bf16(wlo[ks], xhi, acc, 0, 0, 0);
    }
    #pragma unroll
    for (int reg = 0; reg < 4; ++reg) {
      int ro = 16 * T + 4 * q + reg;
      preT[dir * 262144 + ro * 512 + 16 * tt + cc] = acc[reg] + bias[reg];
    }
  }
}

// ---------------------------------------------------------------------------
// K2: sequential LSTM.  grid = 256 blocks: blocks 0,1 do the recurrence
// (proven round-0 MFMA structure); blocks 2..255 are PURE-TIMER heaters:
// zero memory traffic (round-8 forensics: agent-scope flag polling by 2032
// waves saturated the fabric and slowed workers 2.3x — VALUBusy 6% vs the
// 50% free-running FMA would give).  Heaters read s_memrealtime (local
// scalar RTC, 100 MHz) once, run dependent FMAs, and exit unconditionally
// after 12000 ticks (~120us) — no cross-block communication at all.
// Purpose: keep all CUs VALU-busy so SCLK boosts during the 2-CU serial
// phase (round-5: idle chip drops to DVFS floor; workers run ~1.1 GHz).
// ---------------------------------------------------------------------------
__global__ __launch_bounds__(512) void lstm_kernel(
    const float* __restrict__ Whh_f, const float* __restrict__ Whh_b,
    const float* __restrict__ pre,   // [2][512 r][512 t]
    bf16_t* __restrict__ h_all)      // [512][256]
{
  const int tid  = threadIdx.x;

  if (blockIdx.x >= 2) {
    const unsigned long long t0 = __builtin_amdgcn_s_memrealtime();
    float a = 1.0f + (float)tid;
    const float b = 1.0000001f;
    for (;;) {
      #pragma unroll
      for (int it = 0; it < 1024; ++it) a = fmaf(a, b, 1e-7f);
      if (__builtin_amdgcn_s_memrealtime() - t0 > 12000ull) break;
    }
    asm volatile("" :: "v"(a));   // keep the chain alive (no DCE)
    return;
  }

  const int dir = blockIdx.x;
  const float* __restrict__ Whh = dir ? Whh_b : Whh_f;

  const int lane = tid & 63;
  const int w    = tid >> 6;      // wave 0..7
  const int q    = lane >> 4;     // 0..3
  const int cc   = lane & 15;
  const int lt   = cc >> 2;       // local tile 0..3
  const int p    = cc & 3;        // gate index

  // ---- pass 1: global max |Whh| over used elements ----
  float wm = 0.0f;
  #pragma unroll
  for (int LT = 0; LT < 4; ++LT) {
    int rr = 16 * (4 * w + LT) + cc;
    int nn = rr >> 2, pp = rr & 3;
    if (nn < 125) {
      const float* __restrict__ Wrow = Whh + (125 * pp + nn) * 125;
      #pragma unroll
      for (int ks = 0; ks < 2; ++ks)
        #pragma unroll
        for (int jj = 0; jj < 16; ++jj) {
          int k = 64 * ks + 16 * q + jj;
          if (k < 125) wm = fmaxf(wm, fabsf(Wrow[k]));
        }
    }
  }
  #pragma unroll
  for (int off = 1; off < 64; off <<= 1)
    wm = fmaxf(wm, __shfl_xor(wm, off));
  __shared__ float wmx[8];
  if (lane == 0) wmx[w] = wm;
  __syncthreads();
  float wmax = wmx[0];
  #pragma unroll
  for (int u = 1; u < 8; ++u) wmax = fmaxf(wmax, wmx[u]);
  const float s_w  = 127.0f / wmax;
  const float invq = wmax / (127.0f * 127.0f);   // D -> W@h

  // ---- pass 2: quantize A fragments (i8, k = 64ks + 16q + jj) ----
  int4v afrag[4][2];
  #pragma unroll
  for (int LT = 0; LT < 4; ++LT) {
    int rr = 16 * (4 * w + LT) + cc;
    int nn = rr >> 2, pp = rr & 3;
    bool avld = (nn < 125);
    const float* __restrict__ Wrow = Whh + (avld ? (125 * pp + nn) * 125 : 0);
    #pragma unroll
    for (int ks = 0; ks < 2; ++ks) {
      int4v v;
      #pragma unroll
      for (int word = 0; word < 4; ++word) {
        int b = 0;
        #pragma unroll
        for (int byte = 0; byte < 4; ++byte) {
          int jj = 4 * word + byte;
          int k  = 64 * ks + 16 * q + jj;
          int qv = 0;
          if (avld && k < 125)
            qv = (int)__builtin_rintf(Wrow[k] * s_w);
          b |= (qv & 0xFF) << (8 * byte);
        }
        v[word] = b;
      }
      afrag[LT][ks] = v;
    }
  }

  __shared__ __align__(16) char hbuf[2][128];    // int8 h, double buffered
  if (tid < 256) hbuf[tid >> 7][tid & 127] = 0;
  // zero h_all pad columns once (dir 0 only)
  if (dir == 0) {
    #pragma unroll
    for (int u = 0; u < 6; ++u) h_all[tid * 256 + 250 + u] = (bf16_t)0.0f;
  }
  __syncthreads();

  const int   r_lane = 64 * w + 16 * lt + 4 * q + p;
  const int   nset   = 16 * w + 4 * lt + q;
  const float mult   = (p == 2) ? (-2.0f * LOG2E) : (-LOG2E);
  const float sA     = (p == 2) ? 2.0f : 1.0f;
  const float sB     = (p == 2) ? -1.0f : 0.0f;
  const float dscale = mult * invq;              // int D -> exp2 argument
  const float* __restrict__ preR = pre + dir * 262144 + r_lane * 512;
  float c = 0.0f;

  float4 pv_cur = *(const float4*)preR;

  for (int g = 0; g < 128; ++g) {
    float4 pv_nxt = make_float4(0.f, 0.f, 0.f, 0.f);
    if (g < 127) pv_nxt = *(const float4*)(preR + 4 * (g + 1));

    #pragma unroll
    for (int s4 = 0; s4 < 4; ++s4) {
      const int step = 4 * g + s4;
      const int cur  = s4 & 1, nxt = cur ^ 1;
      const float pv = (s4 == 0) ? pv_cur.x : (s4 == 1) ? pv_cur.y
                     : (s4 == 2) ? pv_cur.z : pv_cur.w;
      const float pvm = mult * pv;               // off critical path

      int4v b0 = *(const int4v*)&hbuf[cur][16 * q];
      int4v b1 = *(const int4v*)&hbuf[cur][64 + 16 * q];

      int4v acc[4];
      #pragma unroll
      for (int LT = 0; LT < 4; ++LT) {
        int4v a = (int4v)0;
        a = __builtin_amdgcn_mfma_i32_16x16x64_i8(afrag[LT][0], b0, a, 0, 0, 0);
        a = __builtin_amdgcn_mfma_i32_16x16x64_i8(afrag[LT][1], b1, a, 0, 0, 0);
        acc[LT] = a;
      }

      // select D for (lt, p) from own registers
      int gl[4];
      #pragma unroll
      for (int LT = 0; LT < 4; ++LT) {
        int a01 = (p & 1) ? acc[LT][1] : acc[LT][0];
        int a23 = (p & 1) ? acc[LT][3] : acc[LT][2];
        gl[LT] = (p & 2) ? a23 : a01;
      }
      int b01 = (lt & 1) ? gl[1] : gl[0];
      int b23 = (lt & 1) ? gl[3] : gl[2];
      int gsel = (lt & 2) ? b23 : b01;

      // uniform activation: y = sigmoid(scale*(W@h + pv)); act = sA*y + sB
      float gf  = (float)gsel;
      float xg  = fmaf(gf, dscale, pvm);
      float e   = __builtin_amdgcn_exp2f(xg);
      float y   = __builtin_amdgcn_rcpf(1.0f + e);
      float act = fmaf(y, sA, sB);

      // quad: p0=i, p1=f, p2=g~, p3=o  (flat broadcast tree)
      float b_i = qperm<0x00>(act);
      float b_f = qperm<0x55>(act);
      float b_g = qperm<0xAA>(act);
      float b_o = qperm<0xFF>(act);
      c = fmaf(b_f, c, b_i * b_g);               // c = f*c + i*g~
      float e2 = __builtin_amdgcn_exp2f(-2.0f * LOG2E * c);
      float tc = fmaf(__builtin_amdgcn_rcpf(1.0f + e2), 2.0f, -1.0f);
      float h  = b_o * tc;

      if (p == 0) {
        int qh = (int)__builtin_rintf(h * 127.0f);
        hbuf[nxt][nset] = (char)qh;              // pad units stay exactly 0
        if (nset < 125) {
          int t_orig = dir ? (511 - step) : step;
          h_all[t_orig * 256 + dir * 125 + nset] = (bf16_t)h;
        }
      }
      lds_barrier();
    }
    pv_cur = pv_nxt;
  }
}

// ---------------------------------------------------------------------------
// K3: Ea[j][m] = exp2(C2 * (h @ W1[:, :250].T)[j][m])
//     Eb[j][m] = exp2(C2 * ((h @ W1[:, 250:].T)[j][m] + b1[m]))
// C2 = 2*log2(e).  Storing the EXPONENTIALS halves K4's transcendental count.
// bf16 MFMA, one 16x16 tile/wave.
// ---------------------------------------------------------------------------
__global__ __launch_bounds__(256) void qgemm_kernel(
    const bf16_t* __restrict__ h_all, // [512][256]
    const float* __restrict__ W1,     // [512][500]
    const float* __restrict__ b1,     // [512]
    float* __restrict__ Ea,           // [512][512]
    float* __restrict__ Eb)           // [512][512]
{
  const int tid  = threadIdx.x;
  const int wv   = tid >> 6;
  const int lane = tid & 63;
  const int q    = lane >> 4, cc = lane & 15;
  const int bj   = blockIdx.x & 31;    // j tile
  const int bm   = blockIdx.x >> 5;    // m group
  const int m    = bm * 64 + wv * 16 + cc;   // [0,1024)
  const int j0   = bj * 16;
  const int jA   = j0 + cc;

  const bool isB = (m >= 512);
  const int  row = isB ? (m - 512) : m;
  const int  cof = isB ? 250 : 0;

  f32x4 acc = (f32x4)0.0f;
  #pragma unroll
  for (int ks = 0; ks < 8; ++ks) {
    int kb = 32 * ks + 8 * q;
    bf16x8 a = *(const bf16x8*)&h_all[jA * 256 + kb];
    bf16x8 b;
    #pragma unroll
    for (int jj = 0; jj < 8; ++jj) {
      int k = kb + jj;
      float v = (k < 250) ? W1[row * 500 + cof + k] : 0.0f;
      b[jj] = (bf16_t)v;
    }
    acc = __builtin_amdgcn_mfma_f32_16x16x32_bf16(a, b, acc, 0, 0, 0);
  }

  const float C2 = 2.0f * LOG2E;
  #pragma unroll
  for (int reg = 0; reg < 4; ++reg) {
    int j = j0 + 4 * q + reg;
    float v = acc[reg];
    if (!isB) Ea[j * 512 + m] = __builtin_amdgcn_exp2f(C2 * v);
    else      Eb[j * 512 + (m - 512)] =
                  __builtin_amdgcn_exp2f(C2 * (v + b1[m - 512]));
  }
}

// ---------------------------------------------------------------------------
// K4: out[i][j] = b2 + sum_k W2[k] * tanh(Pa[j,k]+Pb[i,k]+b1[k])
//     tanh = 1 - 2*rcp(1 + Ea[j,k]*Eb[i,k])   (exp2's precomputed in K3)
// k-PAIRED: one rcp per 2 k (exact algebra, overflow-safe).  512 blocks
// (2/CU -> 2 waves/SIMD hides rcp->fma latency), 16i x 32j tile.
// ---------------------------------------------------------------------------
__global__ __launch_bounds__(256) void outer_kernel(
    const float* __restrict__ Ea, const float* __restrict__ Eb,
    const float* __restrict__ W2, const float* __restrict__ b2,
    float* __restrict__ out)
{
  __shared__ float sa2[2][32][36];   // [buf][j][k]
  __shared__ float sb2[2][16][36];   // [buf][i][k]
  __shared__ float sw[2][32];

  const int tid = threadIdx.x;
  const int bi  = blockIdx.x >> 4;       // 0..31 -> i tile of 16
  const int bjx = blockIdx.x & 15;       // 0..15 -> j tile of 32
  const int i0  = bi * 16, j0 = bjx * 32;
  const int ii  = tid & 15;              // output i
  const int jj2 = tid >> 4;              // output j pair: j0 + 2*jj2 + {0,1}

  const int lj  = tid & 31, lk4 = (tid >> 5) * 4;   // sa2 loader coords
  const int li  = tid & 15, lk4b = ((tid >> 4) & 7) * 4; // sb2 loader coords

  float accR0 = 0.0f, accR1 = 0.0f;
  float wsum = 0.0f;

  for (int kc = 0; kc < 16; ++kc) {
    const int buf = kc & 1;
    const int k0  = kc * 32;
    float4 va = *(const float4*)&Ea[(j0 + lj) * 512 + k0 + lk4];
    *(float4*)&sa2[buf][lj][lk4] = va;
    if (tid < 128) {
      float4 vb = *(const float4*)&Eb[(i0 + li) * 512 + k0 + lk4b];
      *(float4*)&sb2[buf][li][lk4b] = vb;
    }
    if (tid < 32) sw[buf][tid] = W2[k0 + tid];
    __syncthreads();

    #pragma unroll 4
    for (int kk = 0; kk < 32; kk += 2) {
      float2 wv = *(const float2*)&sw[buf][kk];
      float2 bv = *(const float2*)&sb2[buf][ii][kk];
      float2 a0 = *(const float2*)&sa2[buf][2 * jj2 + 0][kk];
      float2 a1 = *(const float2*)&sa2[buf][2 * jj2 + 1][kk];
      wsum += wv.x + wv.y;
      {
        float t1  = fmaf(a0.x, bv.x, 1.0f);
        float t2  = fmaf(a0.y, bv.y, 1.0f);
        float den = t1 * t2;
        float num = fmaf(wv.x, t2, wv.y * t1);
        accR0 = fmaf(num, __builtin_amdgcn_rcpf(den), accR0);
      }
      {
        float t1  = fmaf(a1.x, bv.x, 1.0f);
        float t2  = fmaf(a1.y, bv.y, 1.0f);
        float den = t1 * t2;
        float num = fmaf(wv.x, t2, wv.y * t1);
        accR1 = fmaf(num, __builtin_amdgcn_rcpf(den), accR1);
      }
    }
  }

  const float bb = b2[0];
  float2 o;
  o.x = wsum - 2.0f * accR0 + bb;
  o.y = wsum - 2.0f * accR1 + bb;
  *(float2*)&out[(i0 + ii) * 512 + j0 + 2 * jj2] = o;
}

// ---------------------------------------------------------------------------
extern "C" void kernel_launch(void* const* d_in, const int* in_sizes, int n_in,
                              void* d_out, int out_size, void* d_ws, size_t ws_size,
                              hipStream_t stream) {
  const float* emb   = (const float*)d_in[0];
  const float* Wih_f = (const float*)d_in[1];
  const float* Whh_f = (const float*)d_in[2];
  const float* bih_f = (const float*)d_in[3];
  const float* bhh_f = (const float*)d_in[4];
  const float* Wih_b = (const float*)d_in[5];
  const float* Whh_b = (const float*)d_in[6];
  const float* bih_b = (const float*)d_in[7];
  const float* bhh_b = (const float*)d_in[8];
  const float* W1    = (const float*)d_in[9];
  const float* b1    = (const float*)d_in[10];
  const float* W2    = (const float*)d_in[11];
  const float* b2    = (const float*)d_in[12];
  float* out = (float*)d_out;

  char* ws = (char*)d_ws;
  float*    pre   = (float*)ws;                                  // 2 MB
  bf16_t*   h_all = (bf16_t*)(ws + 2 * 1024 * 1024);             // 256 KB
  float*    Ea    = (float*)(ws + 2 * 1024 * 1024 + 256 * 1024); // 1 MB
  float*    Eb    = Ea + 512 * 512;                              // 1 MB

  pre_kernel<<<64, 256, 0, stream>>>(emb, Wih_f, bih_f, bhh_f,
                                     Wih_b, bih_b, bhh_b, pre);
  lstm_kernel<<<256, 512, 0, stream>>>(Whh_f, Whh_b, pre, h_all);
  qgemm_kernel<<<512, 256, 0, stream>>>(h_all, W1, b1, Ea, Eb);
  outer_kernel<<<512, 256, 0, stream>>>(Ea, Eb, W2, b2, out);
}